// Round 6
// baseline (539.986 us; speedup 1.0000x reference)
//
#include <hip/hip_runtime.h>
#include <hip/hip_bf16.h>

#define GG 5000
#define BB 128
#define HH 64
#define EE 100000
#define RR (BB*GG)      // 640000 rows
#define NT (RR/64)      // 10000 tiles of 64 rows
#define EPS 1e-5f

typedef __attribute__((ext_vector_type(8))) short short8;
typedef __attribute__((ext_vector_type(4))) float f32x4;

__device__ __forceinline__ float dot4(const float4 a, const float4 b, float acc) {
  acc = fmaf(a.x, b.x, acc);
  acc = fmaf(a.y, b.y, acc);
  acc = fmaf(a.z, b.z, acc);
  acc = fmaf(a.w, b.w, acc);
  return acc;
}

__device__ __forceinline__ ushort f2b(float f) {
  union { float f; unsigned int u; } c; c.f = f;
  unsigned int u = c.u;
  return (ushort)((u + 0x7FFFu + ((u >> 16) & 1u)) >> 16);
}

// pack 2 float4 (8 consecutive f32) into a bf16 short8
__device__ __forceinline__ short8 pack8(const float4 lo, const float4 hi) {
  union { short8 v; ushort u[8]; } pk;
  pk.u[0] = f2b(lo.x); pk.u[1] = f2b(lo.y); pk.u[2] = f2b(lo.z); pk.u[3] = f2b(lo.w);
  pk.u[4] = f2b(hi.x); pk.u[5] = f2b(hi.y); pk.u[6] = f2b(hi.z); pk.u[7] = f2b(hi.w);
  return pk.v;
}

// ---------- small kernels ----------

// renorm rows of gene_emb AND accumulate column stats of the renormed output.
__global__ void renorm_colsum(const float* __restrict__ X, float* __restrict__ out, int nrows,
                              float* __restrict__ S, float* __restrict__ Q) {
  int w = threadIdx.x >> 6, lane = threadIdx.x & 63;
  float s = 0.f, q = 0.f;
  for (int i = blockIdx.x * 4 + w; i < nrows; i += gridDim.x * 4) {
    float v = X[i * HH + lane];
    float t = v * v;
    #pragma unroll
    for (int m = 1; m < 64; m <<= 1) t += __shfl_xor(t, m);
    float scale = fminf(1.f, 1.f / fmaxf(sqrtf(t), 1e-12f));
    float nv = v * scale;
    out[i * HH + lane] = nv;
    s += nv; q += nv * nv;
  }
  __shared__ float ls[256], lq[256];
  ls[threadIdx.x] = s; lq[threadIdx.x] = q;
  __syncthreads();
  if (w == 0) {
    s = ls[lane] + ls[lane + 64] + ls[lane + 128] + ls[lane + 192];
    q = lq[lane] + lq[lane + 64] + lq[lane + 128] + lq[lane + 192];
    atomicAdd(&S[lane], s);
    atomicAdd(&Q[lane], q);
  }
}

// plain renorm (pert_emb, no stats)
__global__ void renorm_rows(const float* __restrict__ X, float* __restrict__ out, int nrows) {
  int wid = threadIdx.x >> 6, lane = threadIdx.x & 63;
  int i = blockIdx.x * 4 + wid;
  if (i >= nrows) return;
  float v = X[i * HH + lane];
  float s = v * v;
  #pragma unroll
  for (int m = 1; m < 64; m <<= 1) s += __shfl_xor(s, m);
  float scale = fminf(1.f, 1.f / fmaxf(sqrtf(s), 1e-12f));
  out[i * HH + lane] = v * scale;
}

// BN affine (computed inline from S0/Q0) + relu, in place; accumulate new stats.
__global__ void applyBN_colsum(float* __restrict__ X, const float* __restrict__ S0,
                               const float* __restrict__ Q0, const float* __restrict__ gam,
                               const float* __restrict__ bet, int nrows, float inv,
                               float* __restrict__ So, float* __restrict__ Qo) {
  __shared__ float sa[64], sb[64];
  if (threadIdx.x < 64) {
    float m = S0[threadIdx.x] * inv;
    float v = Q0[threadIdx.x] * inv - m * m;
    float a = gam[threadIdx.x] * rsqrtf(fmaxf(v, 0.f) + EPS);
    sa[threadIdx.x] = a;
    sb[threadIdx.x] = bet[threadIdx.x] - m * a;
  }
  __syncthreads();
  int w = threadIdx.x >> 6, lane = threadIdx.x & 63;
  float s = 0.f, q = 0.f;
  for (int i = blockIdx.x * 4 + w; i < nrows; i += gridDim.x * 4) {
    float v = fmaxf(fmaf(sa[lane], X[i * HH + lane], sb[lane]), 0.f);
    X[i * HH + lane] = v;
    s += v; q += v * v;
  }
  __shared__ float ls[256], lq[256];
  ls[threadIdx.x] = s; lq[threadIdx.x] = q;
  __syncthreads();
  if (w == 0) {
    s = ls[lane] + ls[lane + 64] + ls[lane + 128] + ls[lane + 192];
    q = lq[lane] + lq[lane + 64] + lq[lane + 128] + lq[lane + 192];
    atomicAdd(&So[lane], s);
    atomicAdd(&Qo[lane], q);
  }
}

__global__ void edge_deg(const int* __restrict__ dst, const float* __restrict__ ew,
                         float* __restrict__ deg) {
  int e = blockIdx.x * 256 + threadIdx.x;
  if (e < EE) atomicAdd(&deg[dst[e]], ew[e]);
}
// finalize dis = rsqrt(deg+1) AND write self-loop init of agg (one wave owns one row)
__global__ void agg_init(float* __restrict__ deg, const float* __restrict__ rnp,
                         float* __restrict__ agg) {
  int idx = blockIdx.x * 256 + threadIdx.x;
  if (idx < GG * HH) {
    int i = idx >> 6;
    float d = rsqrtf(deg[i] + 1.0f);
    agg[idx] = d * d * rnp[idx];
    if ((idx & 63) == 0) deg[i] = d;
  }
}
__global__ void agg_edges(const int* __restrict__ src, const int* __restrict__ dst,
                          const float* __restrict__ ew, const float* __restrict__ dis,
                          const float* __restrict__ rnp, float* __restrict__ agg) {
  int idx = blockIdx.x * 256 + threadIdx.x;
  int e = idx >> 6, h = idx & 63;
  if (e < EE) {
    int s = src[e], d = dst[e];
    float c = dis[s] * ew[e] * dis[d];
    atomicAdd(&agg[d * HH + h], c * rnp[s * HH + h]);
  }
}

__global__ void gemm_rows64(const float* __restrict__ X, const float* __restrict__ W,
                            const float* __restrict__ bias, float* __restrict__ out,
                            int N, int M) {
  __shared__ float sx[4][HH];
  int wid = threadIdx.x >> 6, lane = threadIdx.x & 63;
  int i = blockIdx.x * 4 + wid;
  if (i < N) sx[wid][lane] = X[i * HH + lane];
  __syncthreads();
  if (i >= N) return;
  for (int j = lane; j < M; j += 64) {
    float acc = bias[j];
    const float* wr = W + j * HH;
    #pragma unroll 16
    for (int h = 0; h < HH; ++h) acc = fmaf(sx[wid][h], wr[h], acc);
    out[i * M + j] = acc;
  }
}

// psum[b,j] += chunked pert@pge; grid (BB, 10)
__global__ void psum_kernel(const int* __restrict__ pert, const float* __restrict__ pge,
                            float* __restrict__ out) {
  int b = blockIdx.x;
  int g0 = blockIdx.y * 500;
  int j = threadIdx.x & 63, part = threadIdx.x >> 6;
  const int* pr = pert + b * GG;
  float a0 = 0.f, a1 = 0.f, a2 = 0.f, a3 = 0.f;
  #pragma unroll 2
  for (int i = 0; i < 124; i += 4) {
    int g = g0 + part + 4 * i;
    a0 = fmaf((float)pr[g],      pge[(g)      * HH + j], a0);
    a1 = fmaf((float)pr[g + 4],  pge[(g + 4)  * HH + j], a1);
    a2 = fmaf((float)pr[g + 8],  pge[(g + 8)  * HH + j], a2);
    a3 = fmaf((float)pr[g + 12], pge[(g + 12) * HH + j], a3);
  }
  { int g = g0 + part + 496; a0 = fmaf((float)pr[g], pge[g * HH + j], a0); }
  float acc = (a0 + a1) + (a2 + a3);
  __shared__ float ls[256];
  ls[threadIdx.x] = acc;
  __syncthreads();
  if (part == 0) atomicAdd(&out[b * HH + j], ls[j] + ls[j + 64] + ls[j + 128] + ls[j + 192]);
}

// cross layer 1 (wave per output) + column stats accumulation
__global__ void cross1_kernel(const float* __restrict__ wv, const float* __restrict__ Wc,
                              const float* __restrict__ bias, float* __restrict__ out,
                              float* __restrict__ S, float* __restrict__ Q) {
  int w = blockIdx.x * 4 + (threadIdx.x >> 6);   // 0..8191
  int lane = threadIdx.x & 63;
  int b = w >> 6, j = w & 63;
  const float* wr = wv + b * GG;
  const float* cr = Wc + j * GG;
  float acc = 0.f;
  #pragma unroll 4
  for (int i = 0; i < 19; ++i) {
    int g = i * 256 + lane * 4;
    const float4 a = *(const float4*)(&wr[g]);
    const float4 c = *(const float4*)(&cr[g]);
    acc = dot4(a, c, acc);
  }
  for (int g = 4864 + lane; g < GG; g += 64)
    acc = fmaf(wr[g], cr[g], acc);
  #pragma unroll
  for (int m = 1; m < 64; m <<= 1) acc += __shfl_xor(acc, m);
  if (lane == 0) {
    float v = bias[j] + acc;
    out[b * HH + j] = v;
    atomicAdd(&S[j], v);
    atomicAdd(&Q[j], v * v);
  }
}

// final head: block = (256 g's) x (16 b's)
__global__ void final_kernel(const float* __restrict__ wv, const float* __restrict__ cross,
                             const float* __restrict__ iw2, const float* __restrict__ ib2,
                             const float* __restrict__ expr, float* __restrict__ out) {
  __shared__ float cs[16][HH];
  const int tid = threadIdx.x;
  const int b0 = blockIdx.y * 16;
  for (int i = tid; i < 16 * HH; i += 256)
    cs[i >> 6][i & 63] = cross[(b0 + (i >> 6)) * HH + (i & 63)];
  __syncthreads();
  int g = blockIdx.x * 256 + tid;
  if (g >= GG) return;
  float rw[65];
  const float* r = iw2 + g * 65;
  #pragma unroll
  for (int i = 0; i < 65; ++i) rw[i] = r[i];
  const float bg = ib2[g];
  for (int bi = 0; bi < 16; ++bi) {
    int b = b0 + bi;
    float acc = fmaf(wv[b * GG + g], rw[0], bg + expr[b * GG + g]);
    #pragma unroll
    for (int h = 0; h < HH; ++h) acc = fmaf(cs[bi][h], rw[1 + h], acc);
    out[b * GG + g] = acc;
  }
}

// ---------- single-block fused MLP: pert_fuse (Lin-BN-ReLU-Lin-BN) + bnp affine ----------
// 256 threads, 4 waves; rows=128, all layers 64 wide; MFMA 16x16x32.
__global__ __launch_bounds__(256)
void pf_fused(const float* __restrict__ psum,
              const float* __restrict__ W1, const float* __restrict__ b1,
              const float* __restrict__ g1, const float* __restrict__ be1,
              const float* __restrict__ W2, const float* __restrict__ b2,
              const float* __restrict__ g2, const float* __restrict__ be2,
              const float* __restrict__ Se, const float* __restrict__ Qe,
              const float* __restrict__ bnpg, const float* __restrict__ bnpb,
              float* __restrict__ fusd, float* __restrict__ az, float* __restrict__ bz) {
  __shared__ __align__(16) char Xb[128 * 128];   // [128][64] bf16
  __shared__ __align__(16) char Tb[128 * 128];   // [128][64] bf16
  __shared__ __align__(16) char Wb[64 * 128];    // [64][64] bf16 (W1 then W2)
  __shared__ float Ss[64], Qs[64], Aa[64], Bbuf[64];
  const int tid = threadIdx.x;
  const int wid = tid >> 6, lane = tid & 63, l15 = lane & 15, l4 = lane >> 4;
  const int j = wid * 16 + l15;

  // stage X = psum [128][64] -> bf16 swizzled
  #pragma unroll
  for (int it = 0; it < 4; ++it) {
    int sid = tid + it * 256;          // 0..1023
    int row = sid >> 3, s = sid & 7;
    const float4 lo = *(const float4*)(&psum[row * 64 + s * 8]);
    const float4 hi = *(const float4*)(&psum[row * 64 + s * 8 + 4]);
    *(short8*)(Xb + row * 128 + ((s ^ (row & 7)) << 4)) = pack8(lo, hi);
  }
  // stage W1 [64][64]
  #pragma unroll
  for (int it = 0; it < 2; ++it) {
    int sid = tid + it * 256;          // 0..511
    int r = sid >> 3, s = sid & 7;
    const float4 lo = *(const float4*)(&W1[r * 64 + s * 8]);
    const float4 hi = *(const float4*)(&W1[r * 64 + s * 8 + 4]);
    *(short8*)(Wb + r * 128 + ((s ^ (r & 7)) << 4)) = pack8(lo, hi);
  }
  __syncthreads();

  // B-frags for GEMM1 (col j)
  short8 bf[2];
  #pragma unroll
  for (int ks = 0; ks < 2; ++ks)
    bf[ks] = *(short8*)(Wb + j * 128 + (((l4 + 4 * ks) ^ (l15 & 7)) << 4));

  // GEMM1: y1[128][64]
  f32x4 d[8];
  #pragma unroll
  for (int rt = 0; rt < 8; ++rt) d[rt] = (f32x4){0.f, 0.f, 0.f, 0.f};
  #pragma unroll
  for (int ks = 0; ks < 2; ++ks)
    #pragma unroll
    for (int rt = 0; rt < 8; ++rt) {
      short8 af = *(short8*)(Xb + (16 * rt + l15) * 128 + (((l4 + 4 * ks) ^ (l15 & 7)) << 4));
      d[rt] = __builtin_amdgcn_mfma_f32_16x16x32_bf16(af, bf[ks], d[rt], 0, 0, 0);
    }
  const float b1v = b1[j];
  float sl = 0.f, ql = 0.f;
  #pragma unroll
  for (int rt = 0; rt < 8; ++rt)
    #pragma unroll
    for (int reg = 0; reg < 4; ++reg) {
      float y = d[rt][reg] + b1v;
      sl += y; ql += y * y;
    }
  sl += __shfl_xor(sl, 16); sl += __shfl_xor(sl, 32);
  ql += __shfl_xor(ql, 16); ql += __shfl_xor(ql, 32);
  if (l4 == 0) { Ss[j] = sl; Qs[j] = ql; }   // one writer per column
  __syncthreads();
  if (tid < 64) {
    float m = Ss[tid] * (1.f / BB), v = Qs[tid] * (1.f / BB) - m * m;
    float a = g1[tid] * rsqrtf(fmaxf(v, 0.f) + EPS);
    Aa[tid] = a; Bbuf[tid] = be1[tid] - m * a;
  }
  __syncthreads();
  // t = relu(a1*y1 + c1) -> Tb ; stage W2 over Wb
  {
    const float a1v = Aa[j], c1v = Bbuf[j];
    const int jhi = j >> 3, jlo = (j & 7) * 2;
    #pragma unroll
    for (int rt = 0; rt < 8; ++rt)
      #pragma unroll
      for (int reg = 0; reg < 4; ++reg) {
        int r = 16 * rt + l4 * 4 + reg;
        float tv = fmaxf(fmaf(a1v, d[rt][reg] + b1v, c1v), 0.f);
        *(ushort*)(Tb + r * 128 + ((jhi ^ (r & 7)) << 4) + jlo) = f2b(tv);
      }
  }
  #pragma unroll
  for (int it = 0; it < 2; ++it) {
    int sid = tid + it * 256;
    int r = sid >> 3, s = sid & 7;
    const float4 lo = *(const float4*)(&W2[r * 64 + s * 8]);
    const float4 hi = *(const float4*)(&W2[r * 64 + s * 8 + 4]);
    *(short8*)(Wb + r * 128 + ((s ^ (r & 7)) << 4)) = pack8(lo, hi);
  }
  __syncthreads();

  short8 bf2[2];
  #pragma unroll
  for (int ks = 0; ks < 2; ++ks)
    bf2[ks] = *(short8*)(Wb + j * 128 + (((l4 + 4 * ks) ^ (l15 & 7)) << 4));
  f32x4 e[8];
  #pragma unroll
  for (int rt = 0; rt < 8; ++rt) e[rt] = (f32x4){0.f, 0.f, 0.f, 0.f};
  #pragma unroll
  for (int ks = 0; ks < 2; ++ks)
    #pragma unroll
    for (int rt = 0; rt < 8; ++rt) {
      short8 af = *(short8*)(Tb + (16 * rt + l15) * 128 + (((l4 + 4 * ks) ^ (l15 & 7)) << 4));
      e[rt] = __builtin_amdgcn_mfma_f32_16x16x32_bf16(af, bf2[ks], e[rt], 0, 0, 0);
    }
  const float b2v = b2[j];
  float sl2 = 0.f, ql2 = 0.f;
  #pragma unroll
  for (int rt = 0; rt < 8; ++rt)
    #pragma unroll
    for (int reg = 0; reg < 4; ++reg) {
      float y = e[rt][reg] + b2v;
      sl2 += y; ql2 += y * y;
    }
  sl2 += __shfl_xor(sl2, 16); sl2 += __shfl_xor(sl2, 32);
  ql2 += __shfl_xor(ql2, 16); ql2 += __shfl_xor(ql2, 32);
  if (l4 == 0) { Ss[j] = sl2; Qs[j] = ql2; }
  __syncthreads();
  if (tid < 64) {
    float m2 = Ss[tid] * (1.f / BB), v2 = fmaxf(Qs[tid] * (1.f / BB) - m2 * m2, 0.f);
    float a2 = g2[tid] * rsqrtf(v2 + EPS);
    Aa[tid] = a2; Bbuf[tid] = be2[tid] - m2 * a2;
    // bnp affine: fusd (BN2 output, no relu) has exact batch mean=be2, var=g2^2*v2/(v2+eps)
    float vf = g2[tid] * g2[tid] * v2 / (v2 + EPS);
    float mf = be2[tid];
    float mb = Se[tid] * (1.f / GG), vb = Qe[tid] * (1.f / GG) - mb * mb;
    float aZ = bnpg[tid] * rsqrtf(fmaxf(vb, 0.f) + vf + EPS);
    az[tid] = aZ;
    bz[tid] = bnpb[tid] - (mb + mf) * aZ;
  }
  __syncthreads();
  const float a2v = Aa[j], c2v = Bbuf[j];
  #pragma unroll
  for (int rt = 0; rt < 8; ++rt)
    #pragma unroll
    for (int reg = 0; reg < 4; ++reg) {
      int r = 16 * rt + l4 * 4 + reg;
      fusd[r * 64 + j] = fmaf(a2v, e[rt][reg] + b2v, c2v);
    }
}

// ---------- single-block fused cross tail: BN1+ReLU -> Lin -> BN2 ----------
__global__ __launch_bounds__(256)
void cross_tail(const float* __restrict__ tmpA, const float* __restrict__ Sc,
                const float* __restrict__ Qc, const float* __restrict__ g1,
                const float* __restrict__ be1, const float* __restrict__ W2,
                const float* __restrict__ b2, const float* __restrict__ g2,
                const float* __restrict__ be2, float* __restrict__ crs) {
  __shared__ __align__(16) char Xb[128 * 128];   // [128][64] bf16
  __shared__ __align__(16) char Wb[64 * 128];
  __shared__ float Ss[64], Qs[64], Aa[64], Bbuf[64];
  const int tid = threadIdx.x;
  const int wid = tid >> 6, lane = tid & 63, l15 = lane & 15, l4 = lane >> 4;
  const int j = wid * 16 + l15;

  if (tid < 64) {
    float m = Sc[tid] * (1.f / BB), v = Qc[tid] * (1.f / BB) - m * m;
    float a = g1[tid] * rsqrtf(fmaxf(v, 0.f) + EPS);
    Aa[tid] = a; Bbuf[tid] = be1[tid] - m * a;
  }
  __syncthreads();
  // stage X = relu(a*tmpA+b) bf16 swizzled
  #pragma unroll
  for (int it = 0; it < 4; ++it) {
    int sid = tid + it * 256;
    int row = sid >> 3, s = sid & 7;
    union { short8 v; ushort u[8]; } pk;
    #pragma unroll
    for (int k = 0; k < 8; ++k) {
      int h = s * 8 + k;
      pk.u[k] = f2b(fmaxf(fmaf(Aa[h], tmpA[row * 64 + h], Bbuf[h]), 0.f));
    }
    *(short8*)(Xb + row * 128 + ((s ^ (row & 7)) << 4)) = pk.v;
  }
  #pragma unroll
  for (int it = 0; it < 2; ++it) {
    int sid = tid + it * 256;
    int r = sid >> 3, s = sid & 7;
    const float4 lo = *(const float4*)(&W2[r * 64 + s * 8]);
    const float4 hi = *(const float4*)(&W2[r * 64 + s * 8 + 4]);
    *(short8*)(Wb + r * 128 + ((s ^ (r & 7)) << 4)) = pack8(lo, hi);
  }
  __syncthreads();

  short8 bf[2];
  #pragma unroll
  for (int ks = 0; ks < 2; ++ks)
    bf[ks] = *(short8*)(Wb + j * 128 + (((l4 + 4 * ks) ^ (l15 & 7)) << 4));
  f32x4 d[8];
  #pragma unroll
  for (int rt = 0; rt < 8; ++rt) d[rt] = (f32x4){0.f, 0.f, 0.f, 0.f};
  #pragma unroll
  for (int ks = 0; ks < 2; ++ks)
    #pragma unroll
    for (int rt = 0; rt < 8; ++rt) {
      short8 af = *(short8*)(Xb + (16 * rt + l15) * 128 + (((l4 + 4 * ks) ^ (l15 & 7)) << 4));
      d[rt] = __builtin_amdgcn_mfma_f32_16x16x32_bf16(af, bf[ks], d[rt], 0, 0, 0);
    }
  const float b2v = b2[j];
  float sl = 0.f, ql = 0.f;
  #pragma unroll
  for (int rt = 0; rt < 8; ++rt)
    #pragma unroll
    for (int reg = 0; reg < 4; ++reg) {
      float y = d[rt][reg] + b2v;
      sl += y; ql += y * y;
    }
  sl += __shfl_xor(sl, 16); sl += __shfl_xor(sl, 32);
  ql += __shfl_xor(ql, 16); ql += __shfl_xor(ql, 32);
  if (l4 == 0) { Ss[j] = sl; Qs[j] = ql; }
  __syncthreads();
  if (tid < 64) {
    float m = Ss[tid] * (1.f / BB), v = Qs[tid] * (1.f / BB) - m * m;
    float a = g2[tid] * rsqrtf(fmaxf(v, 0.f) + EPS);
    Aa[tid] = a; Bbuf[tid] = be2[tid] - m * a;
  }
  __syncthreads();
  const float a2v = Aa[j], c2v = Bbuf[j];
  #pragma unroll
  for (int rt = 0; rt < 8; ++rt)
    #pragma unroll
    for (int reg = 0; reg < 4; ++reg) {
      int r = 16 * rt + l4 * 4 + reg;
      crs[r * 64 + j] = fmaf(a2v, d[rt][reg] + b2v, c2v);
    }
}

// ---------- MFMA big kernel over R=640K rows ----------
// MODE 0: y1 stats -> S1,Q1.  MODE 1: + y2 stats -> S2,Q2 (BN1 affine inline from S1/Q1).
// MODE 2: full recompute -> per-gene head w (BN affines inline; iw1 read from global).

template <int MODE>
__global__ __launch_bounds__(256, 4)
void big_kernel(const float* __restrict__ base, const float* __restrict__ fused,
                const float* __restrict__ az, const float* __restrict__ bz,
                const float* __restrict__ W1, const float* __restrict__ b1,
                const float* __restrict__ W2, const float* __restrict__ b2,
                const float* __restrict__ g1, const float* __restrict__ be1,
                const float* __restrict__ g2, const float* __restrict__ be2,
                const float* __restrict__ iw1, const float* __restrict__ ib1,
                float* __restrict__ S1, float* __restrict__ Q1,
                float* __restrict__ S2, float* __restrict__ Q2,
                float* __restrict__ w_out) {
  constexpr int SMEMB = (MODE == 0) ? 16384 : 32768;
  __shared__ __align__(16) char sm[SMEMB];
  char* smz = sm;                      // [64][64] bf16, 8 KB (steady)
  char* smt = sm + 8192;               // [64][128] bf16, 16 KB (MODE>0)
  float* smwp = (float*)(sm + 24576);  // [4][64] f32 (MODE2)
  char* smw1 = sm;                     // staging overlay: [128][64] bf16
  char* smw2 = sm + 16384;             // [64][128] bf16 (MODE>0)

  const int tid = threadIdx.x;
  const int wid = tid >> 6;
  const int lane = tid & 63;
  const int l15 = lane & 15;
  const int l4 = lane >> 4;
  const int s = tid & 7;

  // ---- stage W1 (and W2) as swizzled bf16 ----
  #pragma unroll
  for (int it = 0; it < 4; ++it) {
    int sid = tid + it * 256;          // 0..1023
    int j = sid >> 3, sl = sid & 7;
    const float4 lo = *(const float4*)(&W1[j * 64 + sl * 8]);
    const float4 hi = *(const float4*)(&W1[j * 64 + sl * 8 + 4]);
    *(short8*)(smw1 + j * 128 + ((sl ^ (j & 7)) << 4)) = pack8(lo, hi);
  }
  if (MODE > 0) {
    #pragma unroll
    for (int it = 0; it < 4; ++it) {
      int sid = tid + it * 256;        // 0..1023
      int n = sid >> 4, sl = sid & 15;
      const float4 lo = *(const float4*)(&W2[n * 128 + sl * 8]);
      const float4 hi = *(const float4*)(&W2[n * 128 + sl * 8 + 4]);
      *(short8*)(smw2 + n * 256 + ((sl ^ (n & 15)) << 4)) = pack8(lo, hi);
    }
  }
  __syncthreads();

  // ---- hoist W fragments ----
  short8 b1f[2][2];
  #pragma unroll
  for (int jt = 0; jt < 2; ++jt)
    #pragma unroll
    for (int ks = 0; ks < 2; ++ks) {
      int j = wid * 32 + jt * 16 + l15;
      b1f[jt][ks] = *(short8*)(smw1 + j * 128 + (((l4 + 4 * ks) ^ (l15 & 7)) << 4));
    }
  short8 b2f[4];
  if (MODE > 0) {
    #pragma unroll
    for (int ks = 0; ks < 4; ++ks) {
      int n = wid * 16 + l15;
      b2f[ks] = *(short8*)(smw2 + n * 256 + (((l4 + 4 * ks) ^ l15) << 4));
    }
  }
  __syncthreads();   // staging region now reusable as z/t

  // ---- per-thread constants (BN affines inline from S/Q) ----
  const float invR = 1.0f / (float)RR;
  const float4 azv0 = *(const float4*)(&az[s * 8]);
  const float4 azv1 = *(const float4*)(&az[s * 8 + 4]);
  const float4 bzv0 = *(const float4*)(&bz[s * 8]);
  const float4 bzv1 = *(const float4*)(&bz[s * 8 + 4]);
  float b1v[2], a1v[2], c1v[2];
  #pragma unroll
  for (int jt = 0; jt < 2; ++jt) {
    int j = wid * 32 + jt * 16 + l15;
    b1v[jt] = b1[j];
    if (MODE > 0) {
      float m = S1[j] * invR, v = Q1[j] * invR - m * m;
      float av = g1[j] * rsqrtf(fmaxf(v, 0.f) + EPS);
      a1v[jt] = av; c1v[jt] = be1[j] - m * av;
    } else { a1v[jt] = 0.f; c1v[jt] = 0.f; }
  }
  const int nn = wid * 16 + l15;
  float b2v = 0, a2v = 0, c2v = 0;
  if (MODE > 0) b2v = b2[nn];
  if (MODE == 2) {
    float m = S2[nn] * invR, v = Q2[nn] * invR - m * m;
    a2v = g2[nn] * rsqrtf(fmaxf(v, 0.f) + EPS);
    c2v = be2[nn] - m * a2v;
  }

  float ss[2] = {0, 0}, qq[2] = {0, 0};
  float s2a = 0, q2a = 0;

  for (int tile = blockIdx.x; tile < NT; tile += gridDim.x) {
    const int r0 = tile * 64;
    const int b0 = r0 / GG;
    const int g0 = r0 - b0 * GG;
    const int rem = GG - g0;

    // ---- stage z tile ----
    #pragma unroll
    for (int it = 0; it < 2; ++it) {
      int sid = tid + it * 256;
      int rloc = sid >> 3;
      int g = g0 + rloc, bb = b0;
      if (rloc >= rem) { g -= GG; bb++; }
      const float4 x0 = *(const float4*)(&base[g * 64 + s * 8]);
      const float4 x1 = *(const float4*)(&base[g * 64 + s * 8 + 4]);
      const float4 f0 = *(const float4*)(&fused[bb * 64 + s * 8]);
      const float4 f1 = *(const float4*)(&fused[bb * 64 + s * 8 + 4]);
      union { short8 v; ushort u[8]; } pk;
      pk.u[0] = f2b(fmaxf(fmaf(azv0.x, x0.x + f0.x, bzv0.x), 0.f));
      pk.u[1] = f2b(fmaxf(fmaf(azv0.y, x0.y + f0.y, bzv0.y), 0.f));
      pk.u[2] = f2b(fmaxf(fmaf(azv0.z, x0.z + f0.z, bzv0.z), 0.f));
      pk.u[3] = f2b(fmaxf(fmaf(azv0.w, x0.w + f0.w, bzv0.w), 0.f));
      pk.u[4] = f2b(fmaxf(fmaf(azv1.x, x1.x + f1.x, bzv1.x), 0.f));
      pk.u[5] = f2b(fmaxf(fmaf(azv1.y, x1.y + f1.y, bzv1.y), 0.f));
      pk.u[6] = f2b(fmaxf(fmaf(azv1.z, x1.z + f1.z, bzv1.z), 0.f));
      pk.u[7] = f2b(fmaxf(fmaf(azv1.w, x1.w + f1.w, bzv1.w), 0.f));
      *(short8*)(smz + rloc * 128 + ((s ^ (rloc & 7)) << 4)) = pk.v;
    }
    __syncthreads();   // (A)

    // ---- GEMM1 ----
    f32x4 d1[4][2];
    #pragma unroll
    for (int rt = 0; rt < 4; ++rt)
      #pragma unroll
      for (int jt = 0; jt < 2; ++jt) d1[rt][jt] = (f32x4){0.f, 0.f, 0.f, 0.f};
    #pragma unroll
    for (int ks = 0; ks < 2; ++ks) {
      short8 af[4];
      #pragma unroll
      for (int rt = 0; rt < 4; ++rt) {
        int r = 16 * rt + l15;
        af[rt] = *(short8*)(smz + r * 128 + (((l4 + 4 * ks) ^ (l15 & 7)) << 4));
      }
      #pragma unroll
      for (int jt = 0; jt < 2; ++jt)
        #pragma unroll
        for (int rt = 0; rt < 4; ++rt)
          d1[rt][jt] = __builtin_amdgcn_mfma_f32_16x16x32_bf16(af[rt], b1f[jt][ks], d1[rt][jt], 0, 0, 0);
    }

    if (MODE == 0) {
      #pragma unroll
      for (int rt = 0; rt < 4; ++rt)
        #pragma unroll
        for (int jt = 0; jt < 2; ++jt)
          #pragma unroll
          for (int reg = 0; reg < 4; ++reg) {
            float y = d1[rt][jt][reg] + b1v[jt];
            ss[jt] += y; qq[jt] += y * y;
          }
      __syncthreads();
    } else {
      // ---- epilogue1: t -> LDS bf16 ----
      #pragma unroll
      for (int rt = 0; rt < 4; ++rt)
        #pragma unroll
        for (int jt = 0; jt < 2; ++jt) {
          int j = wid * 32 + jt * 16 + l15;
          int jhi = j >> 3, jlo = j & 7;
          #pragma unroll
          for (int reg = 0; reg < 4; ++reg) {
            int r = 16 * rt + l4 * 4 + reg;
            float y = d1[rt][jt][reg] + b1v[jt];
            float tv = fmaxf(fmaf(a1v[jt], y, c1v[jt]), 0.f);
            *(ushort*)(smt + r * 256 + ((jhi ^ (r & 15)) << 4) + jlo * 2) = f2b(tv);
          }
        }
      __syncthreads();   // (B)

      // ---- GEMM2 ----
      f32x4 d2[4];
      #pragma unroll
      for (int rt = 0; rt < 4; ++rt) d2[rt] = (f32x4){0.f, 0.f, 0.f, 0.f};
      #pragma unroll
      for (int ks = 0; ks < 4; ++ks) {
        short8 af[4];
        #pragma unroll
        for (int rt = 0; rt < 4; ++rt) {
          int r = 16 * rt + l15;
          af[rt] = *(short8*)(smt + r * 256 + (((l4 + 4 * ks) ^ l15) << 4));
        }
        #pragma unroll
        for (int rt = 0; rt < 4; ++rt)
          d2[rt] = __builtin_amdgcn_mfma_f32_16x16x32_bf16(af[rt], b2f[ks], d2[rt], 0, 0, 0);
      }

      if (MODE == 1) {
        #pragma unroll
        for (int rt = 0; rt < 4; ++rt)
          #pragma unroll
          for (int reg = 0; reg < 4; ++reg) {
            float y2 = d2[rt][reg] + b2v;
            s2a += y2; q2a += y2 * y2;
          }
      } else {  // MODE 2: per-gene head (iw1 direct from global, L2-resident)
        float pa[4][4];
        #pragma unroll
        for (int rt = 0; rt < 4; ++rt)
          #pragma unroll
          for (int reg = 0; reg < 4; ++reg) {
            int rl = 16 * rt + l4 * 4 + reg;
            int g = g0 + rl; if (rl >= rem) g -= GG;
            float o = fmaf(a2v, d2[rt][reg] + b2v, c2v);
            pa[rt][reg] = o * iw1[g * 64 + nn];
          }
        #pragma unroll
        for (int m = 1; m < 16; m <<= 1)
          #pragma unroll
          for (int rt = 0; rt < 4; ++rt)
            #pragma unroll
            for (int reg = 0; reg < 4; ++reg)
              pa[rt][reg] += __shfl_xor(pa[rt][reg], m);
        if (l15 == 0) {
          #pragma unroll
          for (int rt = 0; rt < 4; ++rt)
            #pragma unroll
            for (int reg = 0; reg < 4; ++reg)
              smwp[wid * 64 + 16 * rt + l4 * 4 + reg] = pa[rt][reg];
        }
        __syncthreads();   // (C)
        if (tid < 64) {
          int g = g0 + tid; if (tid >= rem) g -= GG;
          w_out[r0 + tid] = smwp[tid] + smwp[64 + tid] + smwp[128 + tid] + smwp[192 + tid] + ib1[g];
        }
      }
    }
  }

  // ---- flush stats ----
  if (MODE == 0) {
    #pragma unroll
    for (int jt = 0; jt < 2; ++jt) {
      float a = ss[jt], q = qq[jt];
      a += __shfl_xor(a, 16); a += __shfl_xor(a, 32);
      q += __shfl_xor(q, 16); q += __shfl_xor(q, 32);
      if (l4 == 0) {
        atomicAdd(&S1[wid * 32 + jt * 16 + l15], a);
        atomicAdd(&Q1[wid * 32 + jt * 16 + l15], q);
      }
    }
  }
  if (MODE == 1) {
    float a = s2a, q = q2a;
    a += __shfl_xor(a, 16); a += __shfl_xor(a, 32);
    q += __shfl_xor(q, 16); q += __shfl_xor(q, 32);
    if (l4 == 0) {
      atomicAdd(&S2[nn], a);
      atomicAdd(&Q2[nn], q);
    }
  }
}

// ---------- launcher ----------

extern "C" void kernel_launch(void* const* d_in, const int* in_sizes, int n_in,
                              void* d_out, int out_size, void* d_ws, size_t ws_size,
                              hipStream_t stream) {
  const float* expr     = (const float*)d_in[0];
  const int*   pert     = (const int*)d_in[1];
  const int*   ei       = (const int*)d_in[2];
  const float* ew       = (const float*)d_in[3];
  const float* gene_emb = (const float*)d_in[4];
  const float* pert_emb = (const float*)d_in[5];
  const float* bn_emb_g = (const float*)d_in[6];
  const float* bn_emb_b = (const float*)d_in[7];
  const float* sg_W     = (const float*)d_in[8];
  const float* sg_b     = (const float*)d_in[9];
  const float* pf_W1    = (const float*)d_in[10];
  const float* pf_b1    = (const float*)d_in[11];
  const float* pf_g1    = (const float*)d_in[12];
  const float* pf_be1   = (const float*)d_in[13];
  const float* pf_W2    = (const float*)d_in[14];
  const float* pf_b2    = (const float*)d_in[15];
  const float* pf_g2    = (const float*)d_in[16];
  const float* pf_be2   = (const float*)d_in[17];
  const float* bnp_g    = (const float*)d_in[18];
  const float* bnp_b    = (const float*)d_in[19];
  const float* r_W1     = (const float*)d_in[20];
  const float* r_b1     = (const float*)d_in[21];
  const float* r_g1     = (const float*)d_in[22];
  const float* r_be1    = (const float*)d_in[23];
  const float* r_W2     = (const float*)d_in[24];
  const float* r_b2     = (const float*)d_in[25];
  const float* r_g2     = (const float*)d_in[26];
  const float* r_be2    = (const float*)d_in[27];
  const float* iw1      = (const float*)d_in[28];
  const float* ib1      = (const float*)d_in[29];
  const float* c_W1     = (const float*)d_in[30];
  const float* c_b1     = (const float*)d_in[31];
  const float* c_g1     = (const float*)d_in[32];
  const float* c_be1    = (const float*)d_in[33];
  const float* c_W2     = (const float*)d_in[34];
  const float* c_b2     = (const float*)d_in[35];
  const float* c_g2     = (const float*)d_in[36];
  const float* c_be2    = (const float*)d_in[37];
  const float* iw2      = (const float*)d_in[38];
  const float* ib2      = (const float*)d_in[39];
  float* out = (float*)d_out;
  float* ws = (float*)d_ws;

  float* base = ws + 0;        // [G,H]
  float* rnp  = ws + 320000;   // [G,H]
  float* agg  = ws + 640000;   // [G,H]
  float* pge  = ws + 960000;   // [G,H]
  float* wv   = ws + 1280000;  // [B,G]
  // zeroed region [1920000, 1929472)
  float* psum   = ws + 1920000;  // [B,H]
  float* SQ     = ws + 1928192;
  float* S_emb1 = SQ;        float* Q_emb1 = SQ + 64;
  float* S_emb2 = SQ + 128;  float* Q_emb2 = SQ + 192;
  float* S_c1   = SQ + 256;  float* Q_c1   = SQ + 320;
  float* S1   = ws + 1929088;  // [128]
  float* Q1   = ws + 1929216;  // [128]
  float* S2   = ws + 1929344;  // [64]
  float* Q2   = ws + 1929408;  // [64]
  // scratch
  float* fusd = ws + 1929472;  // [B,H]
  float* tmpA = ws + 1937664;  // [B,H]
  float* crs  = ws + 1945856;  // [B,H]
  float* dis  = ws + 1954048;  // [G]
  float* az   = ws + 1959304;  // [64]
  float* bz   = ws + 1959368;  // [64]

  const int* src = ei;
  const int* dst = ei + EE;

  hipMemsetAsync(ws + 1920000, 0, 9472 * sizeof(float), stream);
  hipMemsetAsync(dis, 0, GG * sizeof(float), stream);

  // --- gene embedding path (renorm+stats, BN+relu+stats)
  renorm_colsum<<<80, 256, 0, stream>>>(gene_emb, base, GG, S_emb1, Q_emb1);
  applyBN_colsum<<<80, 256, 0, stream>>>(base, S_emb1, Q_emb1, bn_emb_g, bn_emb_b,
                                         GG, 1.0f / (float)GG, S_emb2, Q_emb2);

  // --- SGConv path
  renorm_rows<<<(GG + 3) / 4, 256, 0, stream>>>(pert_emb, rnp, GG);
  edge_deg<<<(EE + 255) / 256, 256, 0, stream>>>(dst, ew, dis);
  agg_init<<<(GG * HH + 255) / 256, 256, 0, stream>>>(dis, rnp, agg);
  agg_edges<<<(EE * 64 + 255) / 256, 256, 0, stream>>>(src, dst, ew, dis, rnp, agg);
  gemm_rows64<<<(GG + 3) / 4, 256, 0, stream>>>(agg, sg_W, sg_b, pge, GG, HH);
  psum_kernel<<<dim3(BB, 10), 256, 0, stream>>>(pert, pge, psum);

  // --- pert_fuse MLP + bnp affine (single block)
  pf_fused<<<1, 256, 0, stream>>>(psum, pf_W1, pf_b1, pf_g1, pf_be1,
                                  pf_W2, pf_b2, pf_g2, pf_be2,
                                  S_emb2, Q_emb2, bnp_g, bnp_b, fusd, az, bz);

  // --- recovery MLP over 640K rows (3 MFMA passes, BN affines inline)
  big_kernel<0><<<1024, 256, 0, stream>>>(base, fusd, az, bz, r_W1, r_b1, r_W2, r_b2,
                                          r_g1, r_be1, r_g2, r_be2, iw1, ib1,
                                          S1, Q1, S2, Q2, wv);
  big_kernel<1><<<1024, 256, 0, stream>>>(base, fusd, az, bz, r_W1, r_b1, r_W2, r_b2,
                                          r_g1, r_be1, r_g2, r_be2, iw1, ib1,
                                          S1, Q1, S2, Q2, wv);
  big_kernel<2><<<1024, 256, 0, stream>>>(base, fusd, az, bz, r_W1, r_b1, r_W2, r_b2,
                                          r_g1, r_be1, r_g2, r_be2, iw1, ib1,
                                          S1, Q1, S2, Q2, wv);

  // --- cross_gene_state MLP
  cross1_kernel<<<2048, 256, 0, stream>>>(wv, c_W1, c_b1, tmpA, S_c1, Q_c1);
  cross_tail<<<1, 256, 0, stream>>>(tmpA, S_c1, Q_c1, c_g1, c_be1,
                                    c_W2, c_b2, c_g2, c_be2, crs);

  // --- final per-gene head + residual
  final_kernel<<<dim3((GG + 255) / 256, BB / 16), 256, 0, stream>>>(wv, crs, iw2, ib2, expr, out);
}

// Round 8
// 467.320 us; speedup vs baseline: 1.1555x; 1.1555x over previous
//
#include <hip/hip_runtime.h>
#include <hip/hip_bf16.h>

#define GG 5000
#define BB 128
#define HH 64
#define EE 100000
#define RR (BB*GG)      // 640000 rows
#define NT (RR/64)      // 10000 tiles of 64 rows
#define EPS 1e-5f

typedef __attribute__((ext_vector_type(8))) short short8;
typedef __attribute__((ext_vector_type(4))) float f32x4;

__device__ __forceinline__ float dot4(const float4 a, const float4 b, float acc) {
  acc = fmaf(a.x, b.x, acc);
  acc = fmaf(a.y, b.y, acc);
  acc = fmaf(a.z, b.z, acc);
  acc = fmaf(a.w, b.w, acc);
  return acc;
}

__device__ __forceinline__ ushort f2b(float f) {
  union { float f; unsigned int u; } c; c.f = f;
  unsigned int u = c.u;
  return (ushort)((u + 0x7FFFu + ((u >> 16) & 1u)) >> 16);
}

__device__ __forceinline__ short8 pack8(const float4 lo, const float4 hi) {
  union { short8 v; ushort u[8]; } pk;
  pk.u[0] = f2b(lo.x); pk.u[1] = f2b(lo.y); pk.u[2] = f2b(lo.z); pk.u[3] = f2b(lo.w);
  pk.u[4] = f2b(hi.x); pk.u[5] = f2b(hi.y); pk.u[6] = f2b(hi.z); pk.u[7] = f2b(hi.w);
  return pk.v;
}

// ---------- small kernels ----------

__global__ void renorm_colsum(const float* __restrict__ X, float* __restrict__ out, int nrows,
                              float* __restrict__ S, float* __restrict__ Q) {
  int w = threadIdx.x >> 6, lane = threadIdx.x & 63;
  float s = 0.f, q = 0.f;
  for (int i = blockIdx.x * 4 + w; i < nrows; i += gridDim.x * 4) {
    float v = X[i * HH + lane];
    float t = v * v;
    #pragma unroll
    for (int m = 1; m < 64; m <<= 1) t += __shfl_xor(t, m);
    float scale = fminf(1.f, 1.f / fmaxf(sqrtf(t), 1e-12f));
    float nv = v * scale;
    out[i * HH + lane] = nv;
    s += nv; q += nv * nv;
  }
  __shared__ float ls[256], lq[256];
  ls[threadIdx.x] = s; lq[threadIdx.x] = q;
  __syncthreads();
  if (w == 0) {
    s = ls[lane] + ls[lane + 64] + ls[lane + 128] + ls[lane + 192];
    q = lq[lane] + lq[lane + 64] + lq[lane + 128] + lq[lane + 192];
    atomicAdd(&S[lane], s);
    atomicAdd(&Q[lane], q);
  }
}

__global__ void renorm_rows(const float* __restrict__ X, float* __restrict__ out, int nrows) {
  int wid = threadIdx.x >> 6, lane = threadIdx.x & 63;
  int i = blockIdx.x * 4 + wid;
  if (i >= nrows) return;
  float v = X[i * HH + lane];
  float s = v * v;
  #pragma unroll
  for (int m = 1; m < 64; m <<= 1) s += __shfl_xor(s, m);
  float scale = fminf(1.f, 1.f / fmaxf(sqrtf(s), 1e-12f));
  out[i * HH + lane] = v * scale;
}

__global__ void applyBN_colsum(float* __restrict__ X, const float* __restrict__ S0,
                               const float* __restrict__ Q0, const float* __restrict__ gam,
                               const float* __restrict__ bet, int nrows, float inv,
                               float* __restrict__ So, float* __restrict__ Qo) {
  __shared__ float sa[64], sb[64];
  if (threadIdx.x < 64) {
    float m = S0[threadIdx.x] * inv;
    float v = Q0[threadIdx.x] * inv - m * m;
    float a = gam[threadIdx.x] * rsqrtf(fmaxf(v, 0.f) + EPS);
    sa[threadIdx.x] = a;
    sb[threadIdx.x] = bet[threadIdx.x] - m * a;
  }
  __syncthreads();
  int w = threadIdx.x >> 6, lane = threadIdx.x & 63;
  float s = 0.f, q = 0.f;
  for (int i = blockIdx.x * 4 + w; i < nrows; i += gridDim.x * 4) {
    float v = fmaxf(fmaf(sa[lane], X[i * HH + lane], sb[lane]), 0.f);
    X[i * HH + lane] = v;
    s += v; q += v * v;
  }
  __shared__ float ls[256], lq[256];
  ls[threadIdx.x] = s; lq[threadIdx.x] = q;
  __syncthreads();
  if (w == 0) {
    s = ls[lane] + ls[lane + 64] + ls[lane + 128] + ls[lane + 192];
    q = lq[lane] + lq[lane + 64] + lq[lane + 128] + lq[lane + 192];
    atomicAdd(&So[lane], s);
    atomicAdd(&Qo[lane], q);
  }
}

__global__ void edge_deg(const int* __restrict__ dst, const float* __restrict__ ew,
                         float* __restrict__ deg) {
  int e = blockIdx.x * 256 + threadIdx.x;
  if (e < EE) atomicAdd(&deg[dst[e]], ew[e]);
}
__global__ void agg_init(float* __restrict__ deg, const float* __restrict__ rnp,
                         float* __restrict__ agg) {
  int idx = blockIdx.x * 256 + threadIdx.x;
  if (idx < GG * HH) {
    int i = idx >> 6;
    float d = rsqrtf(deg[i] + 1.0f);
    agg[idx] = d * d * rnp[idx];
    if ((idx & 63) == 0) deg[i] = d;
  }
}
__global__ void agg_edges(const int* __restrict__ src, const int* __restrict__ dst,
                          const float* __restrict__ ew, const float* __restrict__ dis,
                          const float* __restrict__ rnp, float* __restrict__ agg) {
  int idx = blockIdx.x * 256 + threadIdx.x;
  int e = idx >> 6, h = idx & 63;
  if (e < EE) {
    int s = src[e], d = dst[e];
    float c = dis[s] * ew[e] * dis[d];
    atomicAdd(&agg[d * HH + h], c * rnp[s * HH + h]);
  }
}

__global__ void gemm_rows64(const float* __restrict__ X, const float* __restrict__ W,
                            const float* __restrict__ bias, float* __restrict__ out,
                            int N, int M) {
  __shared__ float sx[4][HH];
  int wid = threadIdx.x >> 6, lane = threadIdx.x & 63;
  int i = blockIdx.x * 4 + wid;
  if (i < N) sx[wid][lane] = X[i * HH + lane];
  __syncthreads();
  if (i >= N) return;
  for (int j = lane; j < M; j += 64) {
    float acc = bias[j];
    const float* wr = W + j * HH;
    #pragma unroll 16
    for (int h = 0; h < HH; ++h) acc = fmaf(sx[wid][h], wr[h], acc);
    out[i * M + j] = acc;
  }
}

__global__ void psum_kernel(const int* __restrict__ pert, const float* __restrict__ pge,
                            float* __restrict__ out) {
  int b = blockIdx.x;
  int g0 = blockIdx.y * 500;
  int j = threadIdx.x & 63, part = threadIdx.x >> 6;
  const int* pr = pert + b * GG;
  float a0 = 0.f, a1 = 0.f, a2 = 0.f, a3 = 0.f;
  #pragma unroll 2
  for (int i = 0; i < 124; i += 4) {
    int g = g0 + part + 4 * i;
    a0 = fmaf((float)pr[g],      pge[(g)      * HH + j], a0);
    a1 = fmaf((float)pr[g + 4],  pge[(g + 4)  * HH + j], a1);
    a2 = fmaf((float)pr[g + 8],  pge[(g + 8)  * HH + j], a2);
    a3 = fmaf((float)pr[g + 12], pge[(g + 12) * HH + j], a3);
  }
  { int g = g0 + part + 496; a0 = fmaf((float)pr[g], pge[g * HH + j], a0); }
  float acc = (a0 + a1) + (a2 + a3);
  __shared__ float ls[256];
  ls[threadIdx.x] = acc;
  __syncthreads();
  if (part == 0) atomicAdd(&out[b * HH + j], ls[j] + ls[j + 64] + ls[j + 128] + ls[j + 192]);
}

__global__ void cross1_kernel(const float* __restrict__ wv, const float* __restrict__ Wc,
                              const float* __restrict__ bias, float* __restrict__ out,
                              float* __restrict__ S, float* __restrict__ Q) {
  int w = blockIdx.x * 4 + (threadIdx.x >> 6);
  int lane = threadIdx.x & 63;
  int b = w >> 6, j = w & 63;
  const float* wr = wv + b * GG;
  const float* cr = Wc + j * GG;
  float acc = 0.f;
  #pragma unroll 4
  for (int i = 0; i < 19; ++i) {
    int g = i * 256 + lane * 4;
    const float4 a = *(const float4*)(&wr[g]);
    const float4 c = *(const float4*)(&cr[g]);
    acc = dot4(a, c, acc);
  }
  for (int g = 4864 + lane; g < GG; g += 64)
    acc = fmaf(wr[g], cr[g], acc);
  #pragma unroll
  for (int m = 1; m < 64; m <<= 1) acc += __shfl_xor(acc, m);
  if (lane == 0) {
    float v = bias[j] + acc;
    out[b * HH + j] = v;
    atomicAdd(&S[j], v);
    atomicAdd(&Q[j], v * v);
  }
}

__global__ void final_kernel(const float* __restrict__ wv, const float* __restrict__ cross,
                             const float* __restrict__ iw2, const float* __restrict__ ib2,
                             const float* __restrict__ expr, float* __restrict__ out) {
  __shared__ float cs[16][HH];
  const int tid = threadIdx.x;
  const int b0 = blockIdx.y * 16;
  for (int i = tid; i < 16 * HH; i += 256)
    cs[i >> 6][i & 63] = cross[(b0 + (i >> 6)) * HH + (i & 63)];
  __syncthreads();
  int g = blockIdx.x * 256 + tid;
  if (g >= GG) return;
  float rw[65];
  const float* r = iw2 + g * 65;
  #pragma unroll
  for (int i = 0; i < 65; ++i) rw[i] = r[i];
  const float bg = ib2[g];
  for (int bi = 0; bi < 16; ++bi) {
    int b = b0 + bi;
    float acc = fmaf(wv[b * GG + g], rw[0], bg + expr[b * GG + g]);
    #pragma unroll
    for (int h = 0; h < HH; ++h) acc = fmaf(cs[bi][h], rw[1 + h], acc);
    out[b * GG + g] = acc;
  }
}

// ---------- single-block fused MLP: pert_fuse + bnp affine ----------
__global__ __launch_bounds__(256)
void pf_fused(const float* __restrict__ psum,
              const float* __restrict__ W1, const float* __restrict__ b1,
              const float* __restrict__ g1, const float* __restrict__ be1,
              const float* __restrict__ W2, const float* __restrict__ b2,
              const float* __restrict__ g2, const float* __restrict__ be2,
              const float* __restrict__ Se, const float* __restrict__ Qe,
              const float* __restrict__ bnpg, const float* __restrict__ bnpb,
              float* __restrict__ fusd, float* __restrict__ az, float* __restrict__ bz) {
  __shared__ __align__(16) char Xb[128 * 128];
  __shared__ __align__(16) char Tb[128 * 128];
  __shared__ __align__(16) char Wb[64 * 128];
  __shared__ float Ss[64], Qs[64], Aa[64], Bbuf[64];
  const int tid = threadIdx.x;
  const int wid = tid >> 6, lane = tid & 63, l15 = lane & 15, l4 = lane >> 4;
  const int j = wid * 16 + l15;

  #pragma unroll
  for (int it = 0; it < 4; ++it) {
    int sid = tid + it * 256;
    int row = sid >> 3, s = sid & 7;
    const float4 lo = *(const float4*)(&psum[row * 64 + s * 8]);
    const float4 hi = *(const float4*)(&psum[row * 64 + s * 8 + 4]);
    *(short8*)(Xb + row * 128 + ((s ^ (row & 7)) << 4)) = pack8(lo, hi);
  }
  #pragma unroll
  for (int it = 0; it < 2; ++it) {
    int sid = tid + it * 256;
    int r = sid >> 3, s = sid & 7;
    const float4 lo = *(const float4*)(&W1[r * 64 + s * 8]);
    const float4 hi = *(const float4*)(&W1[r * 64 + s * 8 + 4]);
    *(short8*)(Wb + r * 128 + ((s ^ (r & 7)) << 4)) = pack8(lo, hi);
  }
  __syncthreads();

  short8 bf[2];
  #pragma unroll
  for (int ks = 0; ks < 2; ++ks)
    bf[ks] = *(short8*)(Wb + j * 128 + (((l4 + 4 * ks) ^ (l15 & 7)) << 4));

  f32x4 d[8];
  #pragma unroll
  for (int rt = 0; rt < 8; ++rt) d[rt] = (f32x4){0.f, 0.f, 0.f, 0.f};
  #pragma unroll
  for (int ks = 0; ks < 2; ++ks)
    #pragma unroll
    for (int rt = 0; rt < 8; ++rt) {
      short8 af = *(short8*)(Xb + (16 * rt + l15) * 128 + (((l4 + 4 * ks) ^ (l15 & 7)) << 4));
      d[rt] = __builtin_amdgcn_mfma_f32_16x16x32_bf16(af, bf[ks], d[rt], 0, 0, 0);
    }
  const float b1v = b1[j];
  float sl = 0.f, ql = 0.f;
  #pragma unroll
  for (int rt = 0; rt < 8; ++rt)
    #pragma unroll
    for (int reg = 0; reg < 4; ++reg) {
      float y = d[rt][reg] + b1v;
      sl += y; ql += y * y;
    }
  sl += __shfl_xor(sl, 16); sl += __shfl_xor(sl, 32);
  ql += __shfl_xor(ql, 16); ql += __shfl_xor(ql, 32);
  if (l4 == 0) { Ss[j] = sl; Qs[j] = ql; }
  __syncthreads();
  if (tid < 64) {
    float m = Ss[tid] * (1.f / BB), v = Qs[tid] * (1.f / BB) - m * m;
    float a = g1[tid] * rsqrtf(fmaxf(v, 0.f) + EPS);
    Aa[tid] = a; Bbuf[tid] = be1[tid] - m * a;
  }
  __syncthreads();
  {
    const float a1v = Aa[j], c1v = Bbuf[j];
    const int jhi = j >> 3, jlo = (j & 7) * 2;
    #pragma unroll
    for (int rt = 0; rt < 8; ++rt)
      #pragma unroll
      for (int reg = 0; reg < 4; ++reg) {
        int r = 16 * rt + l4 * 4 + reg;
        float tv = fmaxf(fmaf(a1v, d[rt][reg] + b1v, c1v), 0.f);
        *(ushort*)(Tb + r * 128 + ((jhi ^ (r & 7)) << 4) + jlo) = f2b(tv);
      }
  }
  #pragma unroll
  for (int it = 0; it < 2; ++it) {
    int sid = tid + it * 256;
    int r = sid >> 3, s = sid & 7;
    const float4 lo = *(const float4*)(&W2[r * 64 + s * 8]);
    const float4 hi = *(const float4*)(&W2[r * 64 + s * 8 + 4]);
    *(short8*)(Wb + r * 128 + ((s ^ (r & 7)) << 4)) = pack8(lo, hi);
  }
  __syncthreads();

  short8 bf2[2];
  #pragma unroll
  for (int ks = 0; ks < 2; ++ks)
    bf2[ks] = *(short8*)(Wb + j * 128 + (((l4 + 4 * ks) ^ (l15 & 7)) << 4));
  f32x4 e[8];
  #pragma unroll
  for (int rt = 0; rt < 8; ++rt) e[rt] = (f32x4){0.f, 0.f, 0.f, 0.f};
  #pragma unroll
  for (int ks = 0; ks < 2; ++ks)
    #pragma unroll
    for (int rt = 0; rt < 8; ++rt) {
      short8 af = *(short8*)(Tb + (16 * rt + l15) * 128 + (((l4 + 4 * ks) ^ (l15 & 7)) << 4));
      e[rt] = __builtin_amdgcn_mfma_f32_16x16x32_bf16(af, bf2[ks], e[rt], 0, 0, 0);
    }
  const float b2v = b2[j];
  float sl2 = 0.f, ql2 = 0.f;
  #pragma unroll
  for (int rt = 0; rt < 8; ++rt)
    #pragma unroll
    for (int reg = 0; reg < 4; ++reg) {
      float y = e[rt][reg] + b2v;
      sl2 += y; ql2 += y * y;
    }
  sl2 += __shfl_xor(sl2, 16); sl2 += __shfl_xor(sl2, 32);
  ql2 += __shfl_xor(ql2, 16); ql2 += __shfl_xor(ql2, 32);
  if (l4 == 0) { Ss[j] = sl2; Qs[j] = ql2; }
  __syncthreads();
  if (tid < 64) {
    float m2 = Ss[tid] * (1.f / BB), v2 = fmaxf(Qs[tid] * (1.f / BB) - m2 * m2, 0.f);
    float a2 = g2[tid] * rsqrtf(v2 + EPS);
    Aa[tid] = a2; Bbuf[tid] = be2[tid] - m2 * a2;
    float vf = g2[tid] * g2[tid] * v2 / (v2 + EPS);
    float mf = be2[tid];
    float mb = Se[tid] * (1.f / GG), vb = Qe[tid] * (1.f / GG) - mb * mb;
    float aZ = bnpg[tid] * rsqrtf(fmaxf(vb, 0.f) + vf + EPS);
    az[tid] = aZ;
    bz[tid] = bnpb[tid] - (mb + mf) * aZ;
  }
  __syncthreads();
  const float a2v = Aa[j], c2v = Bbuf[j];
  #pragma unroll
  for (int rt = 0; rt < 8; ++rt)
    #pragma unroll
    for (int reg = 0; reg < 4; ++reg) {
      int r = 16 * rt + l4 * 4 + reg;
      fusd[r * 64 + j] = fmaf(a2v, e[rt][reg] + b2v, c2v);
    }
}

// ---------- single-block fused cross tail ----------
__global__ __launch_bounds__(256)
void cross_tail(const float* __restrict__ tmpA, const float* __restrict__ Sc,
                const float* __restrict__ Qc, const float* __restrict__ g1,
                const float* __restrict__ be1, const float* __restrict__ W2,
                const float* __restrict__ b2, const float* __restrict__ g2,
                const float* __restrict__ be2, float* __restrict__ crs) {
  __shared__ __align__(16) char Xb[128 * 128];
  __shared__ __align__(16) char Wb[64 * 128];
  __shared__ float Ss[64], Qs[64], Aa[64], Bbuf[64];
  const int tid = threadIdx.x;
  const int wid = tid >> 6, lane = tid & 63, l15 = lane & 15, l4 = lane >> 4;
  const int j = wid * 16 + l15;

  if (tid < 64) {
    float m = Sc[tid] * (1.f / BB), v = Qc[tid] * (1.f / BB) - m * m;
    float a = g1[tid] * rsqrtf(fmaxf(v, 0.f) + EPS);
    Aa[tid] = a; Bbuf[tid] = be1[tid] - m * a;
  }
  __syncthreads();
  #pragma unroll
  for (int it = 0; it < 4; ++it) {
    int sid = tid + it * 256;
    int row = sid >> 3, s = sid & 7;
    union { short8 v; ushort u[8]; } pk;
    #pragma unroll
    for (int k = 0; k < 8; ++k) {
      int h = s * 8 + k;
      pk.u[k] = f2b(fmaxf(fmaf(Aa[h], tmpA[row * 64 + h], Bbuf[h]), 0.f));
    }
    *(short8*)(Xb + row * 128 + ((s ^ (row & 7)) << 4)) = pk.v;
  }
  #pragma unroll
  for (int it = 0; it < 2; ++it) {
    int sid = tid + it * 256;
    int r = sid >> 3, s = sid & 7;
    const float4 lo = *(const float4*)(&W2[r * 64 + s * 8]);
    const float4 hi = *(const float4*)(&W2[r * 64 + s * 8 + 4]);
    *(short8*)(Wb + r * 128 + ((s ^ (r & 7)) << 4)) = pack8(lo, hi);
  }
  __syncthreads();

  short8 bf[2];
  #pragma unroll
  for (int ks = 0; ks < 2; ++ks)
    bf[ks] = *(short8*)(Wb + j * 128 + (((l4 + 4 * ks) ^ (l15 & 7)) << 4));
  f32x4 d[8];
  #pragma unroll
  for (int rt = 0; rt < 8; ++rt) d[rt] = (f32x4){0.f, 0.f, 0.f, 0.f};
  #pragma unroll
  for (int ks = 0; ks < 2; ++ks)
    #pragma unroll
    for (int rt = 0; rt < 8; ++rt) {
      short8 af = *(short8*)(Xb + (16 * rt + l15) * 128 + (((l4 + 4 * ks) ^ (l15 & 7)) << 4));
      d[rt] = __builtin_amdgcn_mfma_f32_16x16x32_bf16(af, bf[ks], d[rt], 0, 0, 0);
    }
  const float b2v = b2[j];
  float sl = 0.f, ql = 0.f;
  #pragma unroll
  for (int rt = 0; rt < 8; ++rt)
    #pragma unroll
    for (int reg = 0; reg < 4; ++reg) {
      float y = d[rt][reg] + b2v;
      sl += y; ql += y * y;
    }
  sl += __shfl_xor(sl, 16); sl += __shfl_xor(sl, 32);
  ql += __shfl_xor(ql, 16); ql += __shfl_xor(ql, 32);
  if (l4 == 0) { Ss[j] = sl; Qs[j] = ql; }
  __syncthreads();
  if (tid < 64) {
    float m = Ss[tid] * (1.f / BB), v = Qs[tid] * (1.f / BB) - m * m;
    float a = g2[tid] * rsqrtf(fmaxf(v, 0.f) + EPS);
    Aa[tid] = a; Bbuf[tid] = be2[tid] - m * a;
  }
  __syncthreads();
  const float a2v = Aa[j], c2v = Bbuf[j];
  #pragma unroll
  for (int rt = 0; rt < 8; ++rt)
    #pragma unroll
    for (int reg = 0; reg < 4; ++reg) {
      int r = 16 * rt + l4 * 4 + reg;
      crs[r * 64 + j] = fmaf(a2v, d[rt][reg] + b2v, c2v);
    }
}

// ---------- MFMA big kernel over R=640K rows ----------
// MODE 0: y1 stats -> S1,Q1.  MODE 1: + y2 stats -> S2,Q2 (BN1 inline from S1/Q1).
// MODE 2: full recompute -> per-gene head w (BN inline; iw1 staged in LDS).
// R5-proven memory config: 3 blocks/CU, grid 768, MODE2 SMEMB 43008 w/ smiw.

template <int MODE>
__global__ __launch_bounds__(256, 3)
void big_kernel(const float* __restrict__ base, const float* __restrict__ fused,
                const float* __restrict__ az, const float* __restrict__ bz,
                const float* __restrict__ W1, const float* __restrict__ b1,
                const float* __restrict__ W2, const float* __restrict__ b2,
                const float* __restrict__ g1, const float* __restrict__ be1,
                const float* __restrict__ g2, const float* __restrict__ be2,
                const float* __restrict__ iw1, const float* __restrict__ ib1,
                float* __restrict__ S1, float* __restrict__ Q1,
                float* __restrict__ S2, float* __restrict__ Q2,
                float* __restrict__ w_out) {
  constexpr int SMEMB = (MODE == 0) ? 16384 : (MODE == 1) ? 32768 : 43008;
  __shared__ __align__(16) char sm[SMEMB];
  char* smz = sm;                      // [64][64] bf16, 8 KB (steady)
  char* smt = sm + 8192;               // [64][128] bf16, 16 KB (MODE>0)
  float* smiw = (float*)(sm + 24576);  // [64][68] f32 (MODE2)
  float* smwp = (float*)(sm + 41984);  // [4][64] f32 (MODE2)
  char* smw1 = sm;                     // staging overlay: [128][64] bf16
  char* smw2 = sm + 16384;             // [64][128] bf16 (MODE>0)

  const int tid = threadIdx.x;
  const int wid = tid >> 6;
  const int lane = tid & 63;
  const int l15 = lane & 15;
  const int l4 = lane >> 4;
  const int s = tid & 7;

  // ---- stage W1 (and W2) as swizzled bf16 ----
  #pragma unroll
  for (int it = 0; it < 4; ++it) {
    int sid = tid + it * 256;
    int j = sid >> 3, sl = sid & 7;
    const float4 lo = *(const float4*)(&W1[j * 64 + sl * 8]);
    const float4 hi = *(const float4*)(&W1[j * 64 + sl * 8 + 4]);
    *(short8*)(smw1 + j * 128 + ((sl ^ (j & 7)) << 4)) = pack8(lo, hi);
  }
  if (MODE > 0) {
    #pragma unroll
    for (int it = 0; it < 4; ++it) {
      int sid = tid + it * 256;
      int n = sid >> 4, sl = sid & 15;
      const float4 lo = *(const float4*)(&W2[n * 128 + sl * 8]);
      const float4 hi = *(const float4*)(&W2[n * 128 + sl * 8 + 4]);
      *(short8*)(smw2 + n * 256 + ((sl ^ (n & 15)) << 4)) = pack8(lo, hi);
    }
  }
  __syncthreads();

  // ---- hoist W fragments ----
  short8 b1f[2][2];
  #pragma unroll
  for (int jt = 0; jt < 2; ++jt)
    #pragma unroll
    for (int ks = 0; ks < 2; ++ks) {
      int j = wid * 32 + jt * 16 + l15;
      b1f[jt][ks] = *(short8*)(smw1 + j * 128 + (((l4 + 4 * ks) ^ (l15 & 7)) << 4));
    }
  short8 b2f[4];
  if (MODE > 0) {
    #pragma unroll
    for (int ks = 0; ks < 4; ++ks) {
      int n = wid * 16 + l15;
      b2f[ks] = *(short8*)(smw2 + n * 256 + (((l4 + 4 * ks) ^ l15) << 4));
    }
  }
  __syncthreads();

  // ---- per-thread constants (BN affines inline) ----
  const float invR = 1.0f / (float)RR;
  const float4 azv0 = *(const float4*)(&az[s * 8]);
  const float4 azv1 = *(const float4*)(&az[s * 8 + 4]);
  const float4 bzv0 = *(const float4*)(&bz[s * 8]);
  const float4 bzv1 = *(const float4*)(&bz[s * 8 + 4]);
  float b1v[2], a1v[2], c1v[2];
  #pragma unroll
  for (int jt = 0; jt < 2; ++jt) {
    int j = wid * 32 + jt * 16 + l15;
    b1v[jt] = b1[j];
    if (MODE > 0) {
      float m = S1[j] * invR, v = Q1[j] * invR - m * m;
      float av = g1[j] * rsqrtf(fmaxf(v, 0.f) + EPS);
      a1v[jt] = av; c1v[jt] = be1[j] - m * av;
    } else { a1v[jt] = 0.f; c1v[jt] = 0.f; }
  }
  const int nn = wid * 16 + l15;
  float b2v = 0, a2v = 0, c2v = 0;
  if (MODE > 0) b2v = b2[nn];
  if (MODE == 2) {
    float m = S2[nn] * invR, v = Q2[nn] * invR - m * m;
    a2v = g2[nn] * rsqrtf(fmaxf(v, 0.f) + EPS);
    c2v = be2[nn] - m * a2v;
  }

  float ss[2] = {0, 0}, qq[2] = {0, 0};
  float s2a = 0, q2a = 0;

  for (int tile = blockIdx.x; tile < NT; tile += gridDim.x) {
    const int r0 = tile * 64;
    const int b0 = r0 / GG;
    const int g0 = r0 - b0 * GG;
    const int rem = GG - g0;

    // ---- stage z tile ----
    #pragma unroll
    for (int it = 0; it < 2; ++it) {
      int sid = tid + it * 256;
      int rloc = sid >> 3;
      int g = g0 + rloc, bb = b0;
      if (rloc >= rem) { g -= GG; bb++; }
      const float4 x0 = *(const float4*)(&base[g * 64 + s * 8]);
      const float4 x1 = *(const float4*)(&base[g * 64 + s * 8 + 4]);
      const float4 f0 = *(const float4*)(&fused[bb * 64 + s * 8]);
      const float4 f1 = *(const float4*)(&fused[bb * 64 + s * 8 + 4]);
      union { short8 v; ushort u[8]; } pk;
      pk.u[0] = f2b(fmaxf(fmaf(azv0.x, x0.x + f0.x, bzv0.x), 0.f));
      pk.u[1] = f2b(fmaxf(fmaf(azv0.y, x0.y + f0.y, bzv0.y), 0.f));
      pk.u[2] = f2b(fmaxf(fmaf(azv0.z, x0.z + f0.z, bzv0.z), 0.f));
      pk.u[3] = f2b(fmaxf(fmaf(azv0.w, x0.w + f0.w, bzv0.w), 0.f));
      pk.u[4] = f2b(fmaxf(fmaf(azv1.x, x1.x + f1.x, bzv1.x), 0.f));
      pk.u[5] = f2b(fmaxf(fmaf(azv1.y, x1.y + f1.y, bzv1.y), 0.f));
      pk.u[6] = f2b(fmaxf(fmaf(azv1.z, x1.z + f1.z, bzv1.z), 0.f));
      pk.u[7] = f2b(fmaxf(fmaf(azv1.w, x1.w + f1.w, bzv1.w), 0.f));
      *(short8*)(smz + rloc * 128 + ((s ^ (rloc & 7)) << 4)) = pk.v;
    }
    if (MODE == 2) {
      int rloc = tid >> 2, c0 = (tid & 3) * 16;
      int g = g0 + rloc; if (rloc >= rem) g -= GG;
      #pragma unroll
      for (int i = 0; i < 4; ++i)
        *(float4*)(&smiw[rloc * 68 + c0 + 4 * i]) = *(const float4*)(&iw1[g * 64 + c0 + 4 * i]);
    }
    __syncthreads();   // (A)

    // ---- GEMM1 ----
    f32x4 d1[4][2];
    #pragma unroll
    for (int rt = 0; rt < 4; ++rt)
      #pragma unroll
      for (int jt = 0; jt < 2; ++jt) d1[rt][jt] = (f32x4){0.f, 0.f, 0.f, 0.f};
    #pragma unroll
    for (int ks = 0; ks < 2; ++ks) {
      short8 af[4];
      #pragma unroll
      for (int rt = 0; rt < 4; ++rt) {
        int r = 16 * rt + l15;
        af[rt] = *(short8*)(smz + r * 128 + (((l4 + 4 * ks) ^ (l15 & 7)) << 4));
      }
      #pragma unroll
      for (int jt = 0; jt < 2; ++jt)
        #pragma unroll
        for (int rt = 0; rt < 4; ++rt)
          d1[rt][jt] = __builtin_amdgcn_mfma_f32_16x16x32_bf16(af[rt], b1f[jt][ks], d1[rt][jt], 0, 0, 0);
    }

    if (MODE == 0) {
      #pragma unroll
      for (int rt = 0; rt < 4; ++rt)
        #pragma unroll
        for (int jt = 0; jt < 2; ++jt)
          #pragma unroll
          for (int reg = 0; reg < 4; ++reg) {
            float y = d1[rt][jt][reg] + b1v[jt];
            ss[jt] += y; qq[jt] += y * y;
          }
      __syncthreads();
    } else {
      // ---- epilogue1: t -> LDS bf16 ----
      #pragma unroll
      for (int rt = 0; rt < 4; ++rt)
        #pragma unroll
        for (int jt = 0; jt < 2; ++jt) {
          int j = wid * 32 + jt * 16 + l15;
          int jhi = j >> 3, jlo = j & 7;
          #pragma unroll
          for (int reg = 0; reg < 4; ++reg) {
            int r = 16 * rt + l4 * 4 + reg;
            float y = d1[rt][jt][reg] + b1v[jt];
            float tv = fmaxf(fmaf(a1v[jt], y, c1v[jt]), 0.f);
            *(ushort*)(smt + r * 256 + ((jhi ^ (r & 15)) << 4) + jlo * 2) = f2b(tv);
          }
        }
      __syncthreads();   // (B)

      // ---- GEMM2 ----
      f32x4 d2[4];
      #pragma unroll
      for (int rt = 0; rt < 4; ++rt) d2[rt] = (f32x4){0.f, 0.f, 0.f, 0.f};
      #pragma unroll
      for (int ks = 0; ks < 4; ++ks) {
        short8 af[4];
        #pragma unroll
        for (int rt = 0; rt < 4; ++rt) {
          int r = 16 * rt + l15;
          af[rt] = *(short8*)(smt + r * 256 + (((l4 + 4 * ks) ^ l15) << 4));
        }
        #pragma unroll
        for (int rt = 0; rt < 4; ++rt)
          d2[rt] = __builtin_amdgcn_mfma_f32_16x16x32_bf16(af[rt], b2f[ks], d2[rt], 0, 0, 0);
      }

      if (MODE == 1) {
        #pragma unroll
        for (int rt = 0; rt < 4; ++rt)
          #pragma unroll
          for (int reg = 0; reg < 4; ++reg) {
            float y2 = d2[rt][reg] + b2v;
            s2a += y2; q2a += y2 * y2;
          }
      } else {  // MODE 2: per-gene head (iw1 from LDS)
        float pa[4][4];
        #pragma unroll
        for (int rt = 0; rt < 4; ++rt)
          #pragma unroll
          for (int reg = 0; reg < 4; ++reg) {
            int r = 16 * rt + l4 * 4 + reg;
            float o = fmaf(a2v, d2[rt][reg] + b2v, c2v);
            pa[rt][reg] = o * smiw[r * 68 + nn];
          }
        #pragma unroll
        for (int m = 1; m < 16; m <<= 1)
          #pragma unroll
          for (int rt = 0; rt < 4; ++rt)
            #pragma unroll
            for (int reg = 0; reg < 4; ++reg)
              pa[rt][reg] += __shfl_xor(pa[rt][reg], m);
        if (l15 == 0) {
          #pragma unroll
          for (int rt = 0; rt < 4; ++rt)
            #pragma unroll
            for (int reg = 0; reg < 4; ++reg)
              smwp[wid * 64 + 16 * rt + l4 * 4 + reg] = pa[rt][reg];
        }
        __syncthreads();   // (C)
        if (tid < 64) {
          int g = g0 + tid; if (tid >= rem) g -= GG;
          w_out[r0 + tid] = smwp[tid] + smwp[64 + tid] + smwp[128 + tid] + smwp[192 + tid] + ib1[g];
        }
      }
    }
  }

  // ---- flush stats ----
  if (MODE == 0) {
    #pragma unroll
    for (int jt = 0; jt < 2; ++jt) {
      float a = ss[jt], q = qq[jt];
      a += __shfl_xor(a, 16); a += __shfl_xor(a, 32);
      q += __shfl_xor(q, 16); q += __shfl_xor(q, 32);
      if (l4 == 0) {
        atomicAdd(&S1[wid * 32 + jt * 16 + l15], a);
        atomicAdd(&Q1[wid * 32 + jt * 16 + l15], q);
      }
    }
  }
  if (MODE == 1) {
    float a = s2a, q = q2a;
    a += __shfl_xor(a, 16); a += __shfl_xor(a, 32);
    q += __shfl_xor(q, 16); q += __shfl_xor(q, 32);
    if (l4 == 0) {
      atomicAdd(&S2[nn], a);
      atomicAdd(&Q2[nn], q);
    }
  }
}

// ---------- launcher ----------

extern "C" void kernel_launch(void* const* d_in, const int* in_sizes, int n_in,
                              void* d_out, int out_size, void* d_ws, size_t ws_size,
                              hipStream_t stream) {
  const float* expr     = (const float*)d_in[0];
  const int*   pert     = (const int*)d_in[1];
  const int*   ei       = (const int*)d_in[2];
  const float* ew       = (const float*)d_in[3];
  const float* gene_emb = (const float*)d_in[4];
  const float* pert_emb = (const float*)d_in[5];
  const float* bn_emb_g = (const float*)d_in[6];
  const float* bn_emb_b = (const float*)d_in[7];
  const float* sg_W     = (const float*)d_in[8];
  const float* sg_b     = (const float*)d_in[9];
  const float* pf_W1    = (const float*)d_in[10];
  const float* pf_b1    = (const float*)d_in[11];
  const float* pf_g1    = (const float*)d_in[12];
  const float* pf_be1   = (const float*)d_in[13];
  const float* pf_W2    = (const float*)d_in[14];
  const float* pf_b2    = (const float*)d_in[15];
  const float* pf_g2    = (const float*)d_in[16];
  const float* pf_be2   = (const float*)d_in[17];
  const float* bnp_g    = (const float*)d_in[18];
  const float* bnp_b    = (const float*)d_in[19];
  const float* r_W1     = (const float*)d_in[20];
  const float* r_b1     = (const float*)d_in[21];
  const float* r_g1     = (const float*)d_in[22];
  const float* r_be1    = (const float*)d_in[23];
  const float* r_W2     = (const float*)d_in[24];
  const float* r_b2     = (const float*)d_in[25];
  const float* r_g2     = (const float*)d_in[26];
  const float* r_be2    = (const float*)d_in[27];
  const float* iw1      = (const float*)d_in[28];
  const float* ib1      = (const float*)d_in[29];
  const float* c_W1     = (const float*)d_in[30];
  const float* c_b1     = (const float*)d_in[31];
  const float* c_g1     = (const float*)d_in[32];
  const float* c_be1    = (const float*)d_in[33];
  const float* c_W2     = (const float*)d_in[34];
  const float* c_b2     = (const float*)d_in[35];
  const float* c_g2     = (const float*)d_in[36];
  const float* c_be2    = (const float*)d_in[37];
  const float* iw2      = (const float*)d_in[38];
  const float* ib2      = (const float*)d_in[39];
  float* out = (float*)d_out;
  float* ws = (float*)d_ws;

  float* base = ws + 0;        // [G,H]
  float* rnp  = ws + 320000;   // [G,H]
  float* agg  = ws + 640000;   // [G,H]
  float* pge  = ws + 960000;   // [G,H]
  float* wv   = ws + 1280000;  // [B,G]
  // zeroed region [1920000, 1929472)
  float* psum   = ws + 1920000;  // [B,H]
  float* SQ     = ws + 1928192;
  float* S_emb1 = SQ;        float* Q_emb1 = SQ + 64;
  float* S_emb2 = SQ + 128;  float* Q_emb2 = SQ + 192;
  float* S_c1   = SQ + 256;  float* Q_c1   = SQ + 320;
  float* S1   = ws + 1929088;  // [128]
  float* Q1   = ws + 1929216;  // [128]
  float* S2   = ws + 1929344;  // [64]
  float* Q2   = ws + 1929408;  // [64]
  // scratch
  float* fusd = ws + 1929472;  // [B,H]
  float* tmpA = ws + 1937664;  // [B,H]
  float* crs  = ws + 1945856;  // [B,H]
  float* dis  = ws + 1954048;  // [G]
  float* az   = ws + 1959304;  // [64]
  float* bz   = ws + 1959368;  // [64]

  const int* src = ei;
  const int* dst = ei + EE;

  hipMemsetAsync(ws + 1920000, 0, 9472 * sizeof(float), stream);
  hipMemsetAsync(dis, 0, GG * sizeof(float), stream);

  // --- gene embedding path
  renorm_colsum<<<80, 256, 0, stream>>>(gene_emb, base, GG, S_emb1, Q_emb1);
  applyBN_colsum<<<80, 256, 0, stream>>>(base, S_emb1, Q_emb1, bn_emb_g, bn_emb_b,
                                         GG, 1.0f / (float)GG, S_emb2, Q_emb2);

  // --- SGConv path
  renorm_rows<<<(GG + 3) / 4, 256, 0, stream>>>(pert_emb, rnp, GG);
  edge_deg<<<(EE + 255) / 256, 256, 0, stream>>>(dst, ew, dis);
  agg_init<<<(GG * HH + 255) / 256, 256, 0, stream>>>(dis, rnp, agg);
  agg_edges<<<(EE * 64 + 255) / 256, 256, 0, stream>>>(src, dst, ew, dis, rnp, agg);
  gemm_rows64<<<(GG + 3) / 4, 256, 0, stream>>>(agg, sg_W, sg_b, pge, GG, HH);
  psum_kernel<<<dim3(BB, 10), 256, 0, stream>>>(pert, pge, psum);

  // --- pert_fuse MLP + bnp affine (single block)
  pf_fused<<<1, 256, 0, stream>>>(psum, pf_W1, pf_b1, pf_g1, pf_be1,
                                  pf_W2, pf_b2, pf_g2, pf_be2,
                                  S_emb2, Q_emb2, bnp_g, bnp_b, fusd, az, bz);

  // --- recovery MLP over 640K rows (3 MFMA passes, BN affines inline)
  big_kernel<0><<<768, 256, 0, stream>>>(base, fusd, az, bz, r_W1, r_b1, r_W2, r_b2,
                                         r_g1, r_be1, r_g2, r_be2, iw1, ib1,
                                         S1, Q1, S2, Q2, wv);
  big_kernel<1><<<768, 256, 0, stream>>>(base, fusd, az, bz, r_W1, r_b1, r_W2, r_b2,
                                         r_g1, r_be1, r_g2, r_be2, iw1, ib1,
                                         S1, Q1, S2, Q2, wv);
  big_kernel<2><<<768, 256, 0, stream>>>(base, fusd, az, bz, r_W1, r_b1, r_W2, r_b2,
                                         r_g1, r_be1, r_g2, r_be2, iw1, ib1,
                                         S1, Q1, S2, Q2, wv);

  // --- cross_gene_state MLP
  cross1_kernel<<<2048, 256, 0, stream>>>(wv, c_W1, c_b1, tmpA, S_c1, Q_c1);
  cross_tail<<<1, 256, 0, stream>>>(tmpA, S_c1, Q_c1, c_g1, c_be1,
                                    c_W2, c_b2, c_g2, c_be2, crs);

  // --- final per-gene head + residual
  final_kernel<<<dim3((GG + 255) / 256, BB / 16), 256, 0, stream>>>(wv, crs, iw2, ib2, expr, out);
}